// Round 14
// baseline (25.101 us; speedup 1.0000x reference)
//
#include <hip/hip_runtime.h>
#include <stdint.h>

// B=4, T=1024, D=64 causal attention probs + deterministic JAX dropout.
// Single fused kernel, no-max softmax (q,k in [0,1) -> S in [0,8], exp safe).
// 256 blocks x 1024 thr (16 waves -> 4 waves/SIMD for latency hiding).
// Block = 16 interleaved rows {g+64m}; wave wv owns jt = it*16+wv, it=0..3.
// In-register f16 fragment packing (no cvt pass), mfma scores, e=exp(S) kept
// in p[4][4] VGPRs, row sums via 16-lane DPP + LDS, threefry epilogue.
#define TT 1024
#define BB 4

typedef __fp16 fp16x2 __attribute__((ext_vector_type(2)));
typedef __fp16 fp16x8 __attribute__((ext_vector_type(8)));
typedef float  floatx4 __attribute__((ext_vector_type(4)));
union U32H2 { uint32_t u; fp16x2 h; };
union U4H8  { uint4 u; fp16x8 h; };

__device__ __forceinline__ uint32_t rotl32(uint32_t x, int d) {
  return (x << d) | (x >> (32 - d));
}

// JAX partitionable threefry (key(42)) keep decision  [verified R1]
__device__ __forceinline__ bool keep_at(uint32_t i) {
  uint32_t x0 = 0u, x1 = i;
  const uint32_t ks0 = 0u, ks1 = 42u;
  const uint32_t ks2 = 0x1BD11BDAu ^ ks0 ^ ks1;
  x0 += ks0; x1 += ks1;
#define R4(a,b,c,d)                              \
  x0 += x1; x1 = rotl32(x1,(a)); x1 ^= x0;       \
  x0 += x1; x1 = rotl32(x1,(b)); x1 ^= x0;       \
  x0 += x1; x1 = rotl32(x1,(c)); x1 ^= x0;       \
  x0 += x1; x1 = rotl32(x1,(d)); x1 ^= x0;
  R4(13,15,26,6)   x0 += ks1; x1 += ks2 + 1u;
  R4(17,29,16,24)  x0 += ks2; x1 += ks0 + 2u;
  R4(13,15,26,6)   x0 += ks0; x1 += ks1 + 3u;
  R4(17,29,16,24)  x0 += ks1; x1 += ks2 + 4u;
  R4(13,15,26,6)   x0 += ks2; x1 += ks0 + 5u;
#undef R4
  const uint32_t bits = x0 ^ x1;
  const float u = __uint_as_float((bits >> 9) | 0x3f800000u) - 1.0f;
  return u < 0.8f;
}

__device__ __forceinline__ uint32_t pack2(float x, float y) {
  U32H2 t; t.h = __builtin_amdgcn_cvt_pkrtz(x, y);
  return t.u;
}
__device__ __forceinline__ U4H8 pack8(float4 f0, float4 f1) {
  U4H8 d;
  d.u.x = pack2(f0.x, f0.y); d.u.y = pack2(f0.z, f0.w);
  d.u.z = pack2(f1.x, f1.y); d.u.w = pack2(f1.z, f1.w);
  return d;
}

template <int CTRL>
__device__ __forceinline__ float adddpp(float x) {
  const int s =
      __builtin_amdgcn_update_dpp(0, __float_as_int(x), CTRL, 0xF, 0xF, true);
  return x + __int_as_float(s);
}
// sum over the 16 lanes of a (l>>4) group  [verified R11-R13]
__device__ __forceinline__ float radd16(float a) {
  a = adddpp<0xB1>(a);  a = adddpp<0x4E>(a);
  a = adddpp<0x141>(a); a = adddpp<0x140>(a);
  return a;
}

__global__ __launch_bounds__(1024)
void attn_kernel(const float* __restrict__ Q, const float* __restrict__ K,
                 float* __restrict__ O) {
  __shared__ float redS[16][16];      // [row m][wave]

  const int tid  = threadIdx.x;
  const int wv   = tid >> 6, ln = tid & 63;   // wv 0..15
  const int colL = ln & 15;
  const int kgrp = ln >> 4;
  const int g    = blockIdx.x & 63;
  const int b    = blockIdx.x >> 6;

  const float4* Qf = reinterpret_cast<const float4*>(Q) + (size_t)b * TT * 16;
  const float4* Kf = reinterpret_cast<const float4*>(K) + (size_t)b * TT * 16;

  // A-frags (q rows g+64m): lane -> A[row=ln&15][k=kgrp*8+i]
  const int arow = g + 64 * (ln & 15);
  const U4H8 qa0 = pack8(Qf[arow * 16 + kgrp * 2],     Qf[arow * 16 + kgrp * 2 + 1]);
  const U4H8 qa1 = pack8(Qf[arow * 16 + 8 + kgrp * 2], Qf[arow * 16 + 8 + kgrp * 2 + 1]);

  int rowD[4]; uint32_t obase[4];
#pragma unroll
  for (int r = 0; r < 4; ++r) {
    rowD[r]  = g + 64 * (kgrp * 4 + r);
    obase[r] = ((uint32_t)b << 20) | ((uint32_t)rowD[r] << 10);
  }

  // ---- pass A: 4 jt tiles per wave; e = exp(S) kept in regs ----
  float p[4][4];
  float sAcc[4] = {0.f, 0.f, 0.f, 0.f};
#pragma unroll
  for (int it = 0; it < 4; ++it) {
    const int jt = it * 16 + wv;
    const int jrow = jt * 16 + colL;
    const U4H8 kb0 = pack8(Kf[jrow * 16 + kgrp * 2],
                           Kf[jrow * 16 + kgrp * 2 + 1]);
    const U4H8 kb1 = pack8(Kf[jrow * 16 + 8 + kgrp * 2],
                           Kf[jrow * 16 + 8 + kgrp * 2 + 1]);
    floatx4 acc = {0.f, 0.f, 0.f, 0.f};
    acc = __builtin_amdgcn_mfma_f32_16x16x32_f16(qa0.h, kb0.h, acc, 0, 0, 0);
    acc = __builtin_amdgcn_mfma_f32_16x16x32_f16(qa1.h, kb1.h, acc, 0, 0, 0);
    const int col = jt * 16 + colL;
#pragma unroll
    for (int r = 0; r < 4; ++r) {
      const float e = (col <= rowD[r]) ? __expf(acc[r] * 0.125f) : 0.f;
      p[it][r] = e;
      sAcc[r] += e;
    }
  }
#pragma unroll
  for (int r = 0; r < 4; ++r) sAcc[r] = radd16(sAcc[r]);
  if (colL == 0) {
#pragma unroll
    for (int r = 0; r < 4; ++r) redS[kgrp * 4 + r][wv] = sAcc[r];
  }
  __syncthreads();
  float rs[4];
#pragma unroll
  for (int r = 0; r < 4; ++r) {
    const int m = kgrp * 4 + r;
    float S = 0.f;
#pragma unroll
    for (int w = 0; w < 16; ++w) S += redS[m][w];
    rs[r] = 1.25f / S;               // softmax denom + /(1-p) dropout scale
  }

  // ---- epilogue: P*rs + deterministic dropout, store all positions ----
#pragma unroll
  for (int it = 0; it < 4; ++it) {
    const int jt = it * 16 + wv;
#pragma unroll
    for (int r = 0; r < 4; ++r) {
      const int col = jt * 16 + colL;
      float v = 0.f;
      // reg fully masked iff max lane-row (g+64*(12+r)) < jt*16 -> skip threefry
      if (g + 64 * (12 + r) >= jt * 16) {
        const float e = (col <= rowD[r]) ? p[it][r] * rs[r] : 0.f;
        v = keep_at(obase[r] + (uint32_t)col) ? e : 0.f;
      }
      O[obase[r] + (uint32_t)col] = v;   // zeros clear the poison
    }
  }
}

extern "C" void kernel_launch(void* const* d_in, const int* in_sizes, int n_in,
                              void* d_out, int out_size, void* d_ws, size_t ws_size,
                              hipStream_t stream) {
  const float* q = (const float*)d_in[0];
  const float* k = (const float*)d_in[1];
  float* out = (float*)d_out;
  attn_kernel<<<dim3(BB * 64), 1024, 0, stream>>>(q, k, out);
}